// Round 5
// baseline (141.802 us; speedup 1.0000x reference)
//
#include <hip/hip_runtime.h>
#include <hip/hip_bf16.h>

// FiLM + 2-layer preact resnet, fully fused. N=65536, H=256, C=512.
// Round 5: full-K cond in 64KB LDS (no mid-GEMM1 restage), x read from
// global (scatter at FiLM hidden under barrier, coalesced fp32 residual at
// epilogue), r1/r2 reuse cond LDS, 2-slot B pipelines, 6 barriers total.

typedef __attribute__((ext_vector_type(8))) short bf16x8;   // 8 bf16 = 4 VGPR
typedef __attribute__((ext_vector_type(4))) float f32x4;    // MFMA C/D

typedef unsigned short ushort_t;
typedef unsigned int uint_t;

__device__ __forceinline__ ushort_t f2bf(float f) {
  union { float f; uint_t u; } v; v.f = f;
  uint_t u = v.u;
  return (ushort_t)((u + 0x7FFFu + ((u >> 16) & 1u)) >> 16);  // RNE
}
__device__ __forceinline__ float bf2f(ushort_t s) {
  union { uint_t u; float f; } v; v.u = ((uint_t)s) << 16;
  return v.f;
}
__device__ __forceinline__ bf16x8 ldfrag(const ushort_t* p) {
  return *reinterpret_cast<const bf16x8*>(p);
}

// ---------------------------------------------------------------------------
// Pack weights (fp32 row-major [K][Ncols]) into bf16 MFMA-B fragment order:
//   p[((nt*KT + kt)*64 + lane)*8 + j] = W[kt*32 + (lane>>4)*8 + j][nt*16 + (lane&15)]
// ---------------------------------------------------------------------------
__global__ void pack_weights(const float* __restrict__ Wf,
                             const float* __restrict__ W1,
                             const float* __restrict__ W2,
                             ushort_t* __restrict__ p1,
                             ushort_t* __restrict__ pW1,
                             ushort_t* __restrict__ pW2) {
  int u = blockIdx.x * 256 + threadIdx.x;
  if (u < 32768) {
    int lane = u & 63, rest = u >> 6;
    int kt = rest & 15;
    int kb = kt * 32 + (lane >> 4) * 8;
    int col = (rest >> 4) * 16 + (lane & 15);
#pragma unroll
    for (int j = 0; j < 8; ++j)
      p1[(size_t)u * 8 + j] = f2bf(Wf[(size_t)(kb + j) * 512 + col]);
  } else if (u < 40960) {
    int v = u - 32768;
    int lane = v & 63;
    int kt = (v >> 6) & 7;
    int kb = kt * 32 + (lane >> 4) * 8;
    int col = (v >> 9) * 16 + (lane & 15);
#pragma unroll
    for (int j = 0; j < 8; ++j)
      pW1[(size_t)v * 8 + j] = f2bf(W1[(size_t)(kb + j) * 256 + col]);
  } else if (u < 49152) {
    int v = u - 40960;
    int lane = v & 63;
    int kt = (v >> 6) & 7;
    int kb = kt * 32 + (lane >> 4) * 8;
    int col = (v >> 9) * 16 + (lane & 15);
#pragma unroll
    for (int j = 0; j < 8; ++j)
      pW2[(size_t)v * 8 + j] = f2bf(W2[(size_t)(kb + j) * 256 + col]);
  }
}

// ---------------------------------------------------------------------------
// 1 workgroup = 64 rows, 4 waves; wave w owns output cols [w*64, w*64+64).
// LDS 64KB phases:
//   phase 1: cond bf16 [64][512]  (byte = row*1024 + k*2, swz)
//   phase 2: r1 bf16 [64][256] in [0,32K); r2 bf16 [64][256] in [32K,64K)
//   phase 3: out tile fp32 [64][256] (whole 64KB)
// XOR swizzle: byte ^= (row&15)<<4.
// ---------------------------------------------------------------------------
__global__ __launch_bounds__(256, 2)
void film_fused(const float* __restrict__ x, const float* __restrict__ cond,
                const float* __restrict__ b_film, const float* __restrict__ b1,
                const float* __restrict__ b2,
                const ushort_t* __restrict__ p1, const ushort_t* __restrict__ pW1,
                const ushort_t* __restrict__ pW2, float* __restrict__ out) {
  __shared__ __align__(16) char lds[65536];
  char* r2buf = lds + 32768;
  const int r0 = blockIdx.x * 64;
  const int t = threadIdx.x;
  const int w = t >> 6;
  const int l = t & 63;
  const int l15 = l & 15;
  const int lhi = l >> 4;

  // ---- per-lane bias preloads (tiny, L2-hot)
  float bgv[4], bbv[4], b1v[4], b2v[4];
#pragma unroll
  for (int tt = 0; tt < 4; ++tt) {
    int colg = w * 64 + tt * 16 + l15;
    bgv[tt] = b_film[colg];
    bbv[tt] = b_film[256 + colg];
    b1v[tt] = b1[colg];
    b2v[tt] = b2[colg];
  }

  // ---- stage cond full-K -> bf16 LDS [64][512] swz
#pragma unroll
  for (int it = 0; it < 16; ++it) {
    int u = it * 256 + t;
    int row = u >> 6, k8 = u & 63;   // [64 rows][64 units of 8 cols]
    const float4* cs = reinterpret_cast<const float4*>(cond + (size_t)(r0 + row) * 512 + k8 * 8);
    float4 a = cs[0], b = cs[1];
    int byte = row * 1024 + k8 * 16;
    byte ^= ((row & 15) << 4);
    union { bf16x8 v; ushort_t s[8]; } hc;
    hc.s[0]=f2bf(a.x); hc.s[1]=f2bf(a.y); hc.s[2]=f2bf(a.z); hc.s[3]=f2bf(a.w);
    hc.s[4]=f2bf(b.x); hc.s[5]=f2bf(b.y); hc.s[6]=f2bf(b.z); hc.s[7]=f2bf(b.w);
    *reinterpret_cast<bf16x8*>(lds + byte) = hc.v;
  }

  // ---- GEMM1 B preload (ktg=0) before the barrier
  bf16x8 bb[2][8];
#pragma unroll
  for (int tt = 0; tt < 8; ++tt) {
    int nt = (tt < 4) ? (w * 4 + tt) : (16 + w * 4 + (tt - 4));
    bb[0][tt] = ldfrag(p1 + ((nt * 16 + 0) * 64 + l) * 8);
  }
  __syncthreads();   // B1: cond staged

  // ---- GEMM1: gb = cond @ W_film (K=512, 16 ktg, no mid-loop barriers)
  f32x4 acc1[4][8];
#pragma unroll
  for (int m = 0; m < 4; ++m)
#pragma unroll
    for (int n = 0; n < 8; ++n) acc1[m][n] = (f32x4){0.f, 0.f, 0.f, 0.f};

#pragma unroll
  for (int ktg = 0; ktg < 16; ++ktg) {
    const int cur = ktg & 1;
    if (ktg < 15) {
#pragma unroll
      for (int tt = 0; tt < 8; ++tt) {
        int nt = (tt < 4) ? (w * 4 + tt) : (16 + w * 4 + (tt - 4));
        bb[cur ^ 1][tt] = ldfrag(p1 + ((nt * 16 + (ktg + 1)) * 64 + l) * 8);
      }
    }
    bf16x8 afr[4];
#pragma unroll
    for (int m = 0; m < 4; ++m) {
      int row = m * 16 + l15;
      int byte = row * 1024 + ktg * 64 + lhi * 16;
      byte ^= ((row & 15) << 4);
      afr[m] = *reinterpret_cast<const bf16x8*>(lds + byte);
    }
#pragma unroll
    for (int tt = 0; tt < 8; ++tt)
#pragma unroll
      for (int m = 0; m < 4; ++m)
        acc1[m][tt] = __builtin_amdgcn_mfma_f32_16x16x32_bf16(afr[m], bb[cur][tt], acc1[m][tt], 0, 0, 0);
  }

  // ---- issue x loads (FiLM operand) + GEMM2 B preload BEFORE the barrier,
  // so their latency hides under the barrier drain.
  float xv[4][16];
#pragma unroll
  for (int m = 0; m < 4; ++m) {
#pragma unroll
    for (int tt = 0; tt < 4; ++tt) {
#pragma unroll
      for (int reg = 0; reg < 4; ++reg) {
        int row = m * 16 + lhi * 4 + reg;
        int colg = w * 64 + tt * 16 + l15;
        xv[m][tt * 4 + reg] = x[(size_t)(r0 + row) * 256 + colg];
      }
    }
  }
  bf16x8 bb2[2][4];
#pragma unroll
  for (int tt = 0; tt < 4; ++tt) {
    int nt = w * 4 + tt;
    bb2[0][tt] = ldfrag(pW1 + ((nt * 8 + 0) * 64 + l) * 8);
  }
  __syncthreads();   // B2: all cond reads done -> LDS reusable

  // ---- FiLM: r1 = relu(gamma*x + beta) -> bf16 into lds[0,32K)
#pragma unroll
  for (int m = 0; m < 4; ++m) {
#pragma unroll
    for (int tt = 0; tt < 4; ++tt) {
      int colg = w * 64 + tt * 16 + l15;
#pragma unroll
      for (int reg = 0; reg < 4; ++reg) {
        int row = m * 16 + lhi * 4 + reg;
        float g = acc1[m][tt][reg] + bgv[tt];
        float be = acc1[m][4 + tt][reg] + bbv[tt];
        float h = fmaxf(g * xv[m][tt * 4 + reg] + be, 0.f);
        int byte = row * 512 + colg * 2;
        byte ^= ((row & 15) << 4);
        *reinterpret_cast<ushort_t*>(lds + byte) = f2bf(h);
      }
    }
  }
  __syncthreads();   // B3: r1 ready

  // ---- GEMM2: acc2 = r1 @ W1 (K=256, 8 kt)
  f32x4 acc2[4][4];
#pragma unroll
  for (int m = 0; m < 4; ++m)
#pragma unroll
    for (int n = 0; n < 4; ++n) acc2[m][n] = (f32x4){0.f, 0.f, 0.f, 0.f};

#pragma unroll
  for (int kt = 0; kt < 8; ++kt) {
    const int cur = kt & 1;
    if (kt < 7) {
#pragma unroll
      for (int tt = 0; tt < 4; ++tt) {
        int nt = w * 4 + tt;
        bb2[cur ^ 1][tt] = ldfrag(pW1 + ((nt * 8 + (kt + 1)) * 64 + l) * 8);
      }
    }
    bf16x8 afr[4];
#pragma unroll
    for (int m = 0; m < 4; ++m) {
      int row = m * 16 + l15;
      int byte = row * 512 + kt * 64 + lhi * 16;
      byte ^= ((row & 15) << 4);
      afr[m] = *reinterpret_cast<const bf16x8*>(lds + byte);
    }
#pragma unroll
    for (int tt = 0; tt < 4; ++tt)
#pragma unroll
      for (int m = 0; m < 4; ++m)
        acc2[m][tt] = __builtin_amdgcn_mfma_f32_16x16x32_bf16(afr[m], bb2[cur][tt], acc2[m][tt], 0, 0, 0);
  }

  // ---- write r2 = relu(acc2 + b1) -> lds[32K,64K) (disjoint from r1:
  // no barrier needed against other waves' r1 reads). GEMM3 B preload too.
  bf16x8 bb3[2][4];
#pragma unroll
  for (int tt = 0; tt < 4; ++tt) {
    int nt = w * 4 + tt;
    bb3[0][tt] = ldfrag(pW2 + ((nt * 8 + 0) * 64 + l) * 8);
  }
#pragma unroll
  for (int tt = 0; tt < 4; ++tt) {
    int colg = w * 64 + tt * 16 + l15;
#pragma unroll
    for (int m = 0; m < 4; ++m) {
#pragma unroll
      for (int reg = 0; reg < 4; ++reg) {
        int row = m * 16 + lhi * 4 + reg;
        int byte = row * 512 + colg * 2;
        byte ^= ((row & 15) << 4);
        *reinterpret_cast<ushort_t*>(r2buf + byte) = f2bf(fmaxf(acc2[m][tt][reg] + b1v[tt], 0.f));
      }
    }
  }
  __syncthreads();   // B4: r2 ready

  // ---- GEMM3: acc3 = r2 @ W2 (K=256, 8 kt)
  f32x4 acc3[4][4];
#pragma unroll
  for (int m = 0; m < 4; ++m)
#pragma unroll
    for (int n = 0; n < 4; ++n) acc3[m][n] = (f32x4){0.f, 0.f, 0.f, 0.f};

#pragma unroll
  for (int kt = 0; kt < 8; ++kt) {
    const int cur = kt & 1;
    if (kt < 7) {
#pragma unroll
      for (int tt = 0; tt < 4; ++tt) {
        int nt = w * 4 + tt;
        bb3[cur ^ 1][tt] = ldfrag(pW2 + ((nt * 8 + (kt + 1)) * 64 + l) * 8);
      }
    }
    bf16x8 afr[4];
#pragma unroll
    for (int m = 0; m < 4; ++m) {
      int row = m * 16 + l15;
      int byte = row * 512 + kt * 64 + lhi * 16;
      byte ^= ((row & 15) << 4);
      afr[m] = *reinterpret_cast<const bf16x8*>(r2buf + byte);
    }
#pragma unroll
    for (int tt = 0; tt < 4; ++tt)
#pragma unroll
      for (int m = 0; m < 4; ++m)
        acc3[m][tt] = __builtin_amdgcn_mfma_f32_16x16x32_bf16(afr[m], bb3[cur][tt], acc3[m][tt], 0, 0, 0);
  }
  __syncthreads();   // B5: all r2 reads done -> whole LDS free

  // ---- epilogue: fp32 tile [64][256] in whole LDS, coalesced stores with
  // fp32 residual re-read from global (L2-hot from FiLM).
#pragma unroll
  for (int tt = 0; tt < 4; ++tt) {
    int colg = w * 64 + tt * 16 + l15;
#pragma unroll
    for (int m = 0; m < 4; ++m) {
#pragma unroll
      for (int reg = 0; reg < 4; ++reg) {
        int row = m * 16 + lhi * 4 + reg;
        int byte = row * 1024 + colg * 4;
        byte ^= ((row & 15) << 4);
        *reinterpret_cast<float*>(lds + byte) = acc3[m][tt][reg] + b2v[tt];
      }
    }
  }
  __syncthreads();   // B6: tile ready
#pragma unroll
  for (int i = 0; i < 16; ++i) {
    int row = i * 4 + w;             // wave-uniform row; lane l -> 16B unit
    int byte = row * 1024 + l * 16;
    byte ^= ((row & 15) << 4);
    f32x4 v = *reinterpret_cast<const f32x4*>(lds + byte);
    const float4 xres = *reinterpret_cast<const float4*>(x + (size_t)(r0 + row) * 256 + l * 4);
    v.x += xres.x; v.y += xres.y; v.z += xres.z; v.w += xres.w;
    f32x4* op = reinterpret_cast<f32x4*>(out + (size_t)(r0 + row) * 256 + l * 4);
    __builtin_nontemporal_store(v, op);
  }
}

extern "C" void kernel_launch(void* const* d_in, const int* in_sizes, int n_in,
                              void* d_out, int out_size, void* d_ws, size_t ws_size,
                              hipStream_t stream) {
  const float* x      = (const float*)d_in[0];
  const float* cond   = (const float*)d_in[1];
  const float* W_film = (const float*)d_in[2];
  const float* b_film = (const float*)d_in[3];
  const float* W1     = (const float*)d_in[4];
  const float* b1     = (const float*)d_in[5];
  const float* W2     = (const float*)d_in[6];
  const float* b2     = (const float*)d_in[7];
  float* out = (float*)d_out;

  ushort_t* p1  = (ushort_t*)d_ws;      // 512KB
  ushort_t* pW1 = p1 + 262144;          // 128KB
  ushort_t* pW2 = pW1 + 65536;          // 128KB

  hipLaunchKernelGGL(pack_weights, dim3(192), dim3(256), 0, stream,
                     W_film, W1, W2, p1, pW1, pW2);
  hipLaunchKernelGGL(film_fused, dim3(65536 / 64), dim3(256), 0, stream,
                     x, cond, b_film, b1, b2, p1, pW1, pW2, out);
}